// Round 6
// baseline (918.527 us; speedup 1.0000x reference)
//
#include <hip/hip_runtime.h>
#include <hip/hip_bf16.h>
#include <stdint.h>

// JointAttention: B=1, L=512(txt), N=4096(img), HID=1536, H=12, D=128
// Round 8: revert R7's V^T global layout (2.7x fetch amplification, attn
// 352->592). V back to row-major [H][4608][128], R6-proven staging. Keep:
// GEMM global_load_lds fast core, attn launch_bounds(256,4). New: V pack
// VALU hoisted out of the barrier-to-barrier serial window (overlaps PV
// MFMA drain); XCD-aware block swizzle for attn (864 = 8 XCD x 108).
// ws (u16 elems): qb[0) kb[7077888) vb[14155776) ob[21233664)
//   txtb[28311552) imgb[29097984) Wqtb[35389440) Wqib[42467328)
//   Wotb[49545216) Woib[51904512) end 54263808 -> 108.5 MB.

typedef __attribute__((ext_vector_type(8))) short short8;
typedef __attribute__((ext_vector_type(4))) float floatx4;

#define DEV __device__ __forceinline__

DEV float bf2f(uint16_t s) {
  union { uint32_t u; float f; } v;
  v.u = (uint32_t)s << 16;
  return v.f;
}
DEV uint16_t f2bf(float f) {
  __hip_bfloat16 h = __float2bfloat16(f);
  return __builtin_bit_cast(uint16_t, h);
}

// async global->LDS, 16B per lane. LDS dest must be wave-uniform base +
// lane*16; global src is per-lane (pre-swizzled).
DEV void gll16(const uint16_t* g, uint16_t* l) {
  __builtin_amdgcn_global_load_lds(
      (const __attribute__((address_space(1))) void*)g,
      (__attribute__((address_space(3))) void*)l, 16, 0, 0);
}

// Distinguish bf16 vs fp32 buffers (majority vote on exponent sanity).
DEV bool detect_bf16(const void* p) {
  const uint16_t* u = (const uint16_t*)p;
  int sane = 0;
  for (int i = 0; i < 64; ++i) {
    int e = (u[2 * i] >> 7) & 0xFF;
    sane += (e > 90 && e < 145) ? 1 : 0;
  }
  return sane >= 40;
}

DEV short8 load8(const void* base, long idx, bool bf) {
  if (bf) return *(const short8*)((const uint16_t*)base + idx);
  const floatx4* f = (const floatx4*)((const float*)base + idx);
  floatx4 a = f[0], b = f[1];
  short8 r;
  r[0] = (short)f2bf(a[0]); r[1] = (short)f2bf(a[1]);
  r[2] = (short)f2bf(a[2]); r[3] = (short)f2bf(a[3]);
  r[4] = (short)f2bf(b[0]); r[5] = (short)f2bf(b[1]);
  r[6] = (short)f2bf(b[2]); r[7] = (short)f2bf(b[3]);
  return r;
}

DEV float loadElem(const void* base, long idx, bool bf) {
  return bf ? bf2f(((const uint16_t*)base)[idx]) : ((const float*)base)[idx];
}

// ---------------------------------------------------------------------------
// One-time fp32->bf16 (or bf16 copy) of the 6 GEMM operand tensors into ws.
__global__ void convert6(const void* s0, const void* s1, const void* s2,
                         const void* s3, const void* s4, const void* s5,
                         uint16_t* ws) {
  const void* s;
  uint16_t* d;
  long n;
  switch (blockIdx.y) {
    case 0: s = s0; d = ws + 28311552L; n = 786432L; break;   // txt
    case 1: s = s1; d = ws + 29097984L; n = 6291456L; break;  // img
    case 2: s = s2; d = ws + 35389440L; n = 7077888L; break;  // W_txt_qkv
    case 3: s = s3; d = ws + 42467328L; n = 7077888L; break;  // W_img_qkv
    case 4: s = s4; d = ws + 49545216L; n = 2359296L; break;  // W_txt_out
    default: s = s5; d = ws + 51904512L; n = 2359296L; break; // W_img_out
  }
  const bool bf = detect_bf16(s);
  const long stride = (long)gridDim.x * blockDim.x * 8;
  for (long i = ((long)blockIdx.x * blockDim.x + threadIdx.x) * 8; i < n;
       i += stride) {
    if (bf) {
      *(short8*)(d + i) = *(const short8*)((const uint16_t*)s + i);
    } else {
      const floatx4* f = (const floatx4*)((const float*)s + i);
      floatx4 a = f[0], b = f[1];
      short8 r;
      r[0] = (short)f2bf(a[0]); r[1] = (short)f2bf(a[1]);
      r[2] = (short)f2bf(a[2]); r[3] = (short)f2bf(a[3]);
      r[4] = (short)f2bf(b[0]); r[5] = (short)f2bf(b[1]);
      r[6] = (short)f2bf(b[2]); r[7] = (short)f2bf(b[3]);
      *(short8*)(d + i) = r;
    }
  }
}

// ---------------------------------------------------------------------------
// SLOW fallback (fp32 operands): reg staging, single-buffered, 2 barriers.
// Uses first 4096 u16 of each dbuf array.
DEV void gemm_core_slow(const void* A, const void* B, bool abf, bool bbf,
                        long bm, long bn, int K, uint16_t* sA, uint16_t* sB,
                        floatx4 (&acc)[4][4]) {
  const int t = threadIdx.x;
  const int lane = t & 63, wave = t >> 6, l16 = lane & 15, quad = lane >> 4;
  const int srow = t >> 2, c = t & 3, g = c ^ (srow & 3);
  const int wm = (wave >> 1) * 64, wn = (wave & 1) * 64;
  const int fsl = (quad ^ (l16 & 3)) * 8;
  for (int k0 = 0; k0 < K; k0 += 32) {
    short8 a0 = load8(A, (bm + srow) * (long)K + k0 + g * 8, abf);
    short8 a1 = load8(A, (bm + 64 + srow) * (long)K + k0 + g * 8, abf);
    short8 b0 = load8(B, (bn + srow) * (long)K + k0 + g * 8, bbf);
    short8 b1 = load8(B, (bn + 64 + srow) * (long)K + k0 + g * 8, bbf);
    __syncthreads();
    *(short8*)(sA + srow * 32 + c * 8) = a0;
    *(short8*)(sA + (64 + srow) * 32 + c * 8) = a1;
    *(short8*)(sB + srow * 32 + c * 8) = b0;
    *(short8*)(sB + (64 + srow) * 32 + c * 8) = b1;
    __syncthreads();
    short8 af[4], bfr[4];
#pragma unroll
    for (int i = 0; i < 4; ++i) {
      af[i] = *(const short8*)(sA + (wm + i * 16 + l16) * 32 + fsl);
      bfr[i] = *(const short8*)(sB + (wn + i * 16 + l16) * 32 + fsl);
    }
#pragma unroll
    for (int i = 0; i < 4; ++i)
#pragma unroll
      for (int j = 0; j < 4; ++j)
        acc[i][j] = __builtin_amdgcn_mfma_f32_16x16x32_bf16(af[i], bfr[j],
                                                            acc[i][j], 0, 0, 0);
  }
}

// FAST path (bf16 operands): global_load_lds w=16, double-buffered LDS,
// one barrier per K-step. Content layout identical to slow path: slot s of
// row r holds global chunk s^(r&3) (via pre-swizzled per-lane global addr;
// LDS dest is linear wave_base + lane*16 = t*16B per region).
DEV void gemm_core_fast(const uint16_t* A, const uint16_t* B, long bm, long bn,
                        int K, uint16_t* sA, uint16_t* sB,  // each [2][4096]
                        floatx4 (&acc)[4][4]) {
  const int t = threadIdx.x;
  const int lane = t & 63, wave = t >> 6, l16 = lane & 15, quad = lane >> 4;
  const int srow = t >> 2;
  const int gc = (t & 3) ^ (srow & 3);    // pre-swizzled global chunk
  const int wm = (wave >> 1) * 64, wn = (wave & 1) * 64;
  const int fsl = (quad ^ (l16 & 3)) * 8;
  const uint16_t* gA0 = A + (bm + srow) * (long)K + gc * 8;
  const uint16_t* gA1 = A + (bm + 64 + srow) * (long)K + gc * 8;
  const uint16_t* gB0 = B + (bn + srow) * (long)K + gc * 8;
  const uint16_t* gB1 = B + (bn + 64 + srow) * (long)K + gc * 8;
  uint16_t* dA = sA + t * 8;              // linear dest, 16B/lane
  uint16_t* dB = sB + t * 8;
  gll16(gA0, dA);
  gll16(gA1, dA + 2048);
  gll16(gB0, dB);
  gll16(gB1, dB + 2048);
  int buf = 0;
  for (int k0 = 0; k0 < K; k0 += 32) {
    __syncthreads();  // drains this tile's loads; prev frag reads done
    if (k0 + 32 < K) {
      const int nb = (buf ^ 1) * 4096;
      gll16(gA0 + k0 + 32, dA + nb);
      gll16(gA1 + k0 + 32, dA + nb + 2048);
      gll16(gB0 + k0 + 32, dB + nb);
      gll16(gB1 + k0 + 32, dB + nb + 2048);
    }
    const uint16_t* cA = sA + buf * 4096;
    const uint16_t* cB = sB + buf * 4096;
    short8 af[4], bfr[4];
#pragma unroll
    for (int i = 0; i < 4; ++i) {
      af[i] = *(const short8*)(cA + (wm + i * 16 + l16) * 32 + fsl);
      bfr[i] = *(const short8*)(cB + (wn + i * 16 + l16) * 32 + fsl);
    }
#pragma unroll
    for (int i = 0; i < 4; ++i)
#pragma unroll
      for (int j = 0; j < 4; ++j)
        acc[i][j] = __builtin_amdgcn_mfma_f32_16x16x32_bf16(af[i], bfr[j],
                                                            acc[i][j], 0, 0, 0);
    buf ^= 1;
  }
}

// ---------------------------------------------------------------------------
// Merged QKV gemm with fused scatter + rope + q-prescale (SCALE*log2e).
// Column tile = one (tensor tt, head h). q/k/v all row-major [H][4608][128].
__global__ __launch_bounds__(256, 2) void qkv_gemm(
    const void* Atxt, const void* Aimg, const void* Btxt, const void* Bimg,
    const void* rope, const void* det, int conv, uint16_t* qb, uint16_t* kb,
    uint16_t* vb) {
  __shared__ uint16_t sA[2 * 4096], sB[2 * 4096];
  const bool dbf = detect_bf16(det);      // original input dtype (rope)
  const bool bf = conv ? true : dbf;      // A/B operand dtype
  const int bmb = blockIdx.y;
  const long g0 = (long)bmb * 128;        // global seq row of this block
  const bool is_img = bmb >= 4;           // 4*128 == 512 txt rows
  const void* A = is_img ? Aimg : Atxt;
  const void* B = is_img ? Bimg : Btxt;
  const long bmA = is_img ? g0 - 512 : g0;
  const long bn = (long)blockIdx.x * 128;
  floatx4 acc[4][4] = {};
  if (bf)
    gemm_core_fast((const uint16_t*)A, (const uint16_t*)B, bmA, bn, 1536, sA,
                   sB, acc);
  else
    gemm_core_slow(A, B, false, false, bmA, bn, 1536, sA, sB, acc);

  const int t = threadIdx.x, lane = t & 63, wave = t >> 6;
  const int l16 = lane & 15, quad = lane >> 4;
  const int wm = (wave >> 1) * 64, wn = (wave & 1) * 64;
  const int th = blockIdx.x;
  const int tt = th / 12, h = th - tt * 12;
  uint16_t* dst = tt == 0 ? qb : (tt == 1 ? kb : vb);
  const bool do_rope = is_img && (tt < 2);
#pragma unroll
  for (int i = 0; i < 4; ++i)
#pragma unroll
    for (int j = 0; j < 4; ++j)
#pragma unroll
      for (int r = 0; r < 4; ++r) {
        long g = g0 + wm + i * 16 + quad * 4 + r;  // global seq row
        int d = wn + j * 16 + l16;
        float v = acc[i][j][r];
        float p = __shfl_xor(v, 1);  // partner element of the rope pair
        if (do_rope) {
          int dp = d & ~1;
          long ri = (g - 512) * 128 + dp;
          float cc = loadElem(rope, ri, dbf);
          float ss = loadElem(rope, ri + 1, dbf);
          v = (d & 1) ? (v * cc + p * ss) : (v * cc - p * ss);
        }
        if (tt == 0) v *= 0.12751745f;  // D^-0.5 * log2(e)
        dst[((long)h * 4608 + g) * 128 + d] = f2bf(v);
      }
}

// ---------------------------------------------------------------------------
// Merged out-projection gemm.
__global__ __launch_bounds__(256, 2) void out_gemm(
    const uint16_t* Abf, const void* Btxt, const void* Bimg, const void* det,
    int conv, void* out) {
  __shared__ uint16_t sA[2 * 4096], sB[2 * 4096];
  const bool dbf = detect_bf16(det);
  const bool bbf = conv ? true : dbf;
  const int bmb = blockIdx.y;
  const long bm = (long)bmb * 128;
  const void* B = bmb >= 4 ? Bimg : Btxt;
  const long bn = (long)blockIdx.x * 128;
  floatx4 acc[4][4] = {};
  if (bbf)
    gemm_core_fast(Abf, (const uint16_t*)B, bm, bn, 1536, sA, sB, acc);
  else
    gemm_core_slow(Abf, B, true, false, bm, bn, 1536, sA, sB, acc);

  const int t = threadIdx.x, lane = t & 63, wave = t >> 6;
  const int l16 = lane & 15, quad = lane >> 4;
  const int wm = (wave >> 1) * 64, wn = (wave & 1) * 64;
#pragma unroll
  for (int i = 0; i < 4; ++i)
#pragma unroll
    for (int j = 0; j < 4; ++j)
#pragma unroll
      for (int r = 0; r < 4; ++r) {
        long row = bm + wm + i * 16 + quad * 4 + r;
        long col = bn + wn + j * 16 + l16;
        long idx = row * 1536 + col;
        if (dbf) ((uint16_t*)out)[idx] = f2bf(acc[i][j][r]);
        else ((float*)out)[idx] = acc[i][j][r];
      }
}

// ---------------------------------------------------------------------------
// Flash attention, KVBLK=64, single-buffered LDS (40KB), register prefetch.
// Block = (64 q-rows, head); 4 waves x 16 q-rows. V row-major in global
// (contiguous 16KB/tile); LDS-transpose via packed u32 stores. The pack VALU
// is hoisted BEFORE the first barrier (overlaps PV MFMA drain) so the
// barrier-to-barrier serial window is pure LDS stores. XCD-aware block
// swizzle: 864 blocks = 8 XCDs x 108 contiguous, ~1.5 heads per XCD.
// Q pre-scaled by SCALE*log2e -> softmax in exp2 domain. Defer-max THR=11.5.
__global__ __launch_bounds__(256, 4) void attn(
    const uint16_t* __restrict__ qb, const uint16_t* __restrict__ kb,
    const uint16_t* __restrict__ vb, uint16_t* __restrict__ ob) {
  __shared__ uint16_t sK[64 * 128];    // 16KB
  __shared__ uint16_t sVt[128 * 64];   // 16KB, [d][64 keys] chunk-swizzled
  __shared__ uint16_t sP[4][16 * 64];  // 8KB

  const int t = threadIdx.x;
  const int lane = t & 63, wave = t >> 6;
  const int l16 = lane & 15, quad = lane >> 4;
  // XCD swizzle: bijective since 864 % 8 == 0 (108 blocks per XCD chunk)
  const int bid = blockIdx.y * 72 + blockIdx.x;
  const int sw = (bid & 7) * 108 + (bid >> 3);
  const int h = sw / 72;
  const int q0 = (sw - h * 72) * 64 + wave * 16;

  const uint16_t* Qh = qb + (long)h * 4608 * 128;
  const uint16_t* Kh = kb + (long)h * 4608 * 128;
  const uint16_t* Vh = vb + (long)h * 4608 * 128;

  short8 aq[4];
#pragma unroll
  for (int dk = 0; dk < 4; ++dk)
    aq[dk] = *(const short8*)(Qh + (long)(q0 + l16) * 128 + dk * 32 + quad * 8);

  short8 ones;
#pragma unroll
  for (int j = 0; j < 8; ++j) ones[j] = (short)0x3F80;  // bf16 1.0

  float m_i[4] = {-1e30f, -1e30f, -1e30f, -1e30f};
  floatx4 accL = {};
  floatx4 accO[8] = {};

  const int krow = t >> 2;        // 0..63
  const int kcb = (t & 3) * 4;    // K chunk base (4 chunks of 8 elems)
  const int vk = (t & 31) * 2;    // V key pair
  const int vdb = (t >> 5) * 8;   // V d base x2 halves (8 d's per half)

  uint16_t* pw = &sP[wave][0];

  short8 kreg[4], vreg[4];
  uint32_t vpk[16];

  auto loadKV = [&](int key0) {
    const uint16_t* kp = Kh + (long)(key0 + krow) * 128 + kcb * 8;
    kreg[0] = *(const short8*)(kp);
    kreg[1] = *(const short8*)(kp + 8);
    kreg[2] = *(const short8*)(kp + 16);
    kreg[3] = *(const short8*)(kp + 24);
    const uint16_t* vp = Vh + (long)(key0 + vk) * 128 + vdb * 2;
    vreg[0] = *(const short8*)(vp);
    vreg[1] = *(const short8*)(vp + 8);
    vreg[2] = *(const short8*)(vp + 128);
    vreg[3] = *(const short8*)(vp + 136);
  };
  // pack V pairs into u32 (VALU; overlapped with PV MFMA drain)
  auto packV = [&]() {
#pragma unroll
    for (int hf = 0; hf < 2; ++hf)
#pragma unroll
      for (int j = 0; j < 8; ++j)
        vpk[hf * 8 + j] = (uint16_t)vreg[hf][j] |
                          ((uint32_t)(uint16_t)vreg[2 + hf][j] << 16);
  };
  // pure LDS stores (the serial window)
  auto writeKV = [&]() {
#pragma unroll
    for (int j = 0; j < 4; ++j)
      *(short8*)(sK + krow * 128 + (((kcb + j) ^ (krow & 15)) * 8)) = kreg[j];
    char* vd = (char*)&sVt[0];
#pragma unroll
    for (int hf = 0; hf < 2; ++hf)
#pragma unroll
      for (int j = 0; j < 8; ++j) {
        const int d = vdb * 2 + hf * 8 + j;
        *(uint32_t*)(vd + d * 128 + (((vk >> 3) ^ (d & 7)) * 16) +
                     (vk & 7) * 2) = vpk[hf * 8 + j];
      }
  };

  loadKV(0);
  packV();
  writeKV();
  __syncthreads();

  for (int kt = 0; kt < 72; ++kt) {
    // issue next tile's global loads; they land during this tile's compute
    if (kt < 71) loadKV((kt + 1) * 64);

    // S = Q K^T (already in log2 domain)
    floatx4 sc4[4] = {};
    __builtin_amdgcn_s_setprio(1);
#pragma unroll
    for (int ns = 0; ns < 4; ++ns) {
      const int row = ns * 16 + l16;
#pragma unroll
      for (int dk = 0; dk < 4; ++dk) {
        short8 bk = *(const short8*)(sK + row * 128 +
                                     (((dk * 4 + quad) ^ l16) * 8));
        sc4[ns] = __builtin_amdgcn_mfma_f32_16x16x32_bf16(aq[dk], bk, sc4[ns],
                                                          0, 0, 0);
      }
    }
    __builtin_amdgcn_s_setprio(0);

    // online softmax (log2 domain), defer-max
    float mx[4];
#pragma unroll
    for (int r = 0; r < 4; ++r) {
      float a = fmaxf(fmaxf(sc4[0][r], sc4[1][r]),
                      fmaxf(sc4[2][r], sc4[3][r]));
      a = fmaxf(a, __shfl_xor(a, 1));
      a = fmaxf(a, __shfl_xor(a, 2));
      a = fmaxf(a, __shfl_xor(a, 4));
      a = fmaxf(a, __shfl_xor(a, 8));
      mx[r] = a;
    }
    float ex = fmaxf(fmaxf(mx[0] - m_i[0], mx[1] - m_i[1]),
                     fmaxf(mx[2] - m_i[2], mx[3] - m_i[3]));
    if (!__all(ex <= 11.5f)) {
#pragma unroll
      for (int r = 0; r < 4; ++r) {
        float mn = fmaxf(m_i[r], mx[r]);
        float al = exp2f(m_i[r] - mn);
        m_i[r] = mn;
        accL[r] *= al;
#pragma unroll
        for (int vt = 0; vt < 8; ++vt) accO[vt][r] *= al;
      }
    }
#pragma unroll
    for (int ns = 0; ns < 4; ++ns)
#pragma unroll
      for (int r = 0; r < 4; ++r) sc4[ns][r] = exp2f(sc4[ns][r] - m_i[r]);

    // P -> per-wave stash (C->A transpose), chunk-swizzled (8 chunks/row)
#pragma unroll
    for (int ns = 0; ns < 4; ++ns)
#pragma unroll
      for (int r = 0; r < 4; ++r) {
        const int row = quad * 4 + r;
        const int col = ns * 16 + l16;
        *(uint16_t*)((char*)pw + row * 128 +
                     (((col >> 3) ^ (row & 7)) * 16) + (col & 7) * 2) =
            f2bf(sc4[ns][r]);
      }
    asm volatile("s_waitcnt lgkmcnt(0)" ::: "memory");  // stash drain

    short8 pa[2];
#pragma unroll
    for (int ks = 0; ks < 2; ++ks)
      pa[ks] = *(const short8*)((char*)pw + l16 * 128 +
                                (((ks * 4 + quad) ^ (l16 & 7)) * 16));
    __builtin_amdgcn_s_setprio(1);
    accL = __builtin_amdgcn_mfma_f32_16x16x32_bf16(pa[0], ones, accL, 0, 0, 0);
    accL = __builtin_amdgcn_mfma_f32_16x16x32_bf16(pa[1], ones, accL, 0, 0, 0);
#pragma unroll
    for (int vt = 0; vt < 8; ++vt) {
      const int d = vt * 16 + l16;
#pragma unroll
      for (int ks = 0; ks < 2; ++ks) {
        short8 bv = *(const short8*)((const char*)&sVt[0] + d * 128 +
                                     (((ks * 4 + quad) ^ (d & 7)) * 16));
        accO[vt] = __builtin_amdgcn_mfma_f32_16x16x32_bf16(pa[ks], bv,
                                                           accO[vt], 0, 0, 0);
      }
    }
    __builtin_amdgcn_s_setprio(0);

    // pack next tile's V while PV MFMAs drain (vmcnt wait lands here,
    // overlapped with matrix-pipe work instead of inside the serial window)
    if (kt < 71) packV();

    __syncthreads();  // all waves done reading sK/sVt
    if (kt < 71) {
      writeKV();      // pure LDS stores
      __syncthreads();
    }
  }

#pragma unroll
  for (int r = 0; r < 4; ++r) {
    const long row = q0 + quad * 4 + r;
    const float inv = 1.f / accL[r];
#pragma unroll
    for (int vt = 0; vt < 8; ++vt)
      ob[row * 1536 + h * 128 + vt * 16 + l16] = f2bf(accO[vt][r] * inv);
  }
}

// ---------------------------------------------------------------------------
extern "C" void kernel_launch(void* const* d_in, const int* in_sizes, int n_in,
                              void* d_out, int out_size, void* d_ws,
                              size_t ws_size, hipStream_t stream) {
  const void* txt = d_in[0];
  const void* img = d_in[1];
  const void* rope = d_in[2];
  const void* Wtq = d_in[3];
  const void* Wiq = d_in[4];
  const void* Wto = d_in[5];
  const void* Wio = d_in[6];

  uint16_t* ws = (uint16_t*)d_ws;
  uint16_t* qb = ws;                  // [12][4608][128]
  uint16_t* kb = ws + 7077888L;
  uint16_t* vb = ws + 14155776L;      // [12][4608][128] row-major
  uint16_t* ob = ws + 21233664L;      // [4608][1536]

  const size_t NEED = 108527616ULL;   // 54,263,808 u16 elems
  const int conv = (ws_size >= NEED) ? 1 : 0;

  const void *Atxt = txt, *Aimg = img;
  const void *Bqt = Wtq, *Bqi = Wiq, *Bot = Wto, *Boi = Wio;
  if (conv) {
    convert6<<<dim3(864, 6), 256, 0, stream>>>(txt, img, Wtq, Wiq, Wto, Wio,
                                               ws);
    Atxt = ws + 28311552L;
    Aimg = ws + 29097984L;
    Bqt = ws + 35389440L;
    Bqi = ws + 42467328L;
    Bot = ws + 49545216L;
    Boi = ws + 51904512L;
  }

  qkv_gemm<<<dim3(36, 36), 256, 0, stream>>>(Atxt, Aimg, Bqt, Bqi, rope, txt,
                                             conv, qb, kb, vb);
  attn<<<dim3(72, 12), 256, 0, stream>>>(qb, kb, vb, ob);
  out_gemm<<<dim3(12, 36), 256, 0, stream>>>(ob, Bot, Boi, txt, conv, d_out);
}

// Round 8
// 629.778 us; speedup vs baseline: 1.4585x; 1.4585x over previous
//
#include <hip/hip_runtime.h>
#include <hip/hip_bf16.h>
#include <stdint.h>

// JointAttention: B=1, L=512(txt), N=4096(img), HID=1536, H=12, D=128
// Round 10 = Round 9 resubmission (R9 bench died in harness async runtime,
// "Trio nursery" exception — no kernel diagnostic; source re-audited:
// occupancy/VGPR fit, bijective swizzle, bounds, uniform barriers all OK).
//  - GEMMs: reg-staged core (measured ~21us faster than global_load_lds core
//    here; R5/R6 "total - attn" 290-300 vs R4 268).
//  - attn: R4 structure at launch_bounds(256,3) [R6's (256,4) clamped VGPR to
//    64 -> 25MB/dispatch scratch spill, attn 352->630]. packV hoisted out of
//    the serial window (VGPR ~100 fits the ~168 cap at 3 waves/EU); XCD
//    swizzle (bijective, 864 = 8 x 108) for K/V L2 locality.
// Verification signals: attn VGPR ~90-105, WRITE_SIZE 13.8MB (no spill).
// ws (u16 elems): qb[0) kb[7077888) vb[14155776) ob[21233664)
//   txtb[28311552) imgb[29097984) Wqtb[35389440) Wqib[42467328)
//   Wotb[49545216) Woib[51904512) end 54263808 -> 108.5 MB.

typedef __attribute__((ext_vector_type(8))) short short8;
typedef __attribute__((ext_vector_type(4))) float floatx4;

#define DEV __device__ __forceinline__

DEV float bf2f(uint16_t s) {
  union { uint32_t u; float f; } v;
  v.u = (uint32_t)s << 16;
  return v.f;
}
DEV uint16_t f2bf(float f) {
  __hip_bfloat16 h = __float2bfloat16(f);
  return __builtin_bit_cast(uint16_t, h);
}

// Distinguish bf16 vs fp32 buffers (majority vote on exponent sanity).
DEV bool detect_bf16(const void* p) {
  const uint16_t* u = (const uint16_t*)p;
  int sane = 0;
  for (int i = 0; i < 64; ++i) {
    int e = (u[2 * i] >> 7) & 0xFF;
    sane += (e > 90 && e < 145) ? 1 : 0;
  }
  return sane >= 40;
}

DEV short8 load8(const void* base, long idx, bool bf) {
  if (bf) return *(const short8*)((const uint16_t*)base + idx);
  const floatx4* f = (const floatx4*)((const float*)base + idx);
  floatx4 a = f[0], b = f[1];
  short8 r;
  r[0] = (short)f2bf(a[0]); r[1] = (short)f2bf(a[1]);
  r[2] = (short)f2bf(a[2]); r[3] = (short)f2bf(a[3]);
  r[4] = (short)f2bf(b[0]); r[5] = (short)f2bf(b[1]);
  r[6] = (short)f2bf(b[2]); r[7] = (short)f2bf(b[3]);
  return r;
}

DEV float loadElem(const void* base, long idx, bool bf) {
  return bf ? bf2f(((const uint16_t*)base)[idx]) : ((const float*)base)[idx];
}

// ---------------------------------------------------------------------------
// One-time fp32->bf16 (or bf16 copy) of the 6 GEMM operand tensors into ws.
__global__ void convert6(const void* s0, const void* s1, const void* s2,
                         const void* s3, const void* s4, const void* s5,
                         uint16_t* ws) {
  const void* s;
  uint16_t* d;
  long n;
  switch (blockIdx.y) {
    case 0: s = s0; d = ws + 28311552L; n = 786432L; break;   // txt
    case 1: s = s1; d = ws + 29097984L; n = 6291456L; break;  // img
    case 2: s = s2; d = ws + 35389440L; n = 7077888L; break;  // W_txt_qkv
    case 3: s = s3; d = ws + 42467328L; n = 7077888L; break;  // W_img_qkv
    case 4: s = s4; d = ws + 49545216L; n = 2359296L; break;  // W_txt_out
    default: s = s5; d = ws + 51904512L; n = 2359296L; break; // W_img_out
  }
  const bool bf = detect_bf16(s);
  const long stride = (long)gridDim.x * blockDim.x * 8;
  for (long i = ((long)blockIdx.x * blockDim.x + threadIdx.x) * 8; i < n;
       i += stride) {
    if (bf) {
      *(short8*)(d + i) = *(const short8*)((const uint16_t*)s + i);
    } else {
      const floatx4* f = (const floatx4*)((const float*)s + i);
      floatx4 a = f[0], b = f[1];
      short8 r;
      r[0] = (short)f2bf(a[0]); r[1] = (short)f2bf(a[1]);
      r[2] = (short)f2bf(a[2]); r[3] = (short)f2bf(a[3]);
      r[4] = (short)f2bf(b[0]); r[5] = (short)f2bf(b[1]);
      r[6] = (short)f2bf(b[2]); r[7] = (short)f2bf(b[3]);
      *(short8*)(d + i) = r;
    }
  }
}

// ---------------------------------------------------------------------------
// acc[4][4] for C tile (bm,bn) of A[M,K] * B[N,K]^T via bf16 MFMA.
// 128x128 tile, BK=32, register staging + ds_write_b128, XOR chunk swizzle.
DEV void gemm_core(const void* A, const void* B, bool abf, bool bbf, long bm,
                   long bn, int K, uint16_t* sA, uint16_t* sB,
                   floatx4 (&acc)[4][4]) {
  const int t = threadIdx.x;
  const int lane = t & 63, wave = t >> 6, l16 = lane & 15, quad = lane >> 4;
  const int srow = t >> 2, c = t & 3, g = c ^ (srow & 3);
  const int wm = (wave >> 1) * 64, wn = (wave & 1) * 64;
  const int fsl = (quad ^ (l16 & 3)) * 8;
  for (int k0 = 0; k0 < K; k0 += 32) {
    short8 a0 = load8(A, (bm + srow) * (long)K + k0 + g * 8, abf);
    short8 a1 = load8(A, (bm + 64 + srow) * (long)K + k0 + g * 8, abf);
    short8 b0 = load8(B, (bn + srow) * (long)K + k0 + g * 8, bbf);
    short8 b1 = load8(B, (bn + 64 + srow) * (long)K + k0 + g * 8, bbf);
    __syncthreads();  // prev-iter frag reads done before overwrite
    *(short8*)(sA + srow * 32 + c * 8) = a0;
    *(short8*)(sA + (64 + srow) * 32 + c * 8) = a1;
    *(short8*)(sB + srow * 32 + c * 8) = b0;
    *(short8*)(sB + (64 + srow) * 32 + c * 8) = b1;
    __syncthreads();
    short8 af[4], bfr[4];
#pragma unroll
    for (int i = 0; i < 4; ++i) {
      af[i] = *(const short8*)(sA + (wm + i * 16 + l16) * 32 + fsl);
      bfr[i] = *(const short8*)(sB + (wn + i * 16 + l16) * 32 + fsl);
    }
#pragma unroll
    for (int i = 0; i < 4; ++i)
#pragma unroll
      for (int j = 0; j < 4; ++j)
        acc[i][j] = __builtin_amdgcn_mfma_f32_16x16x32_bf16(af[i], bfr[j],
                                                            acc[i][j], 0, 0, 0);
  }
}

// ---------------------------------------------------------------------------
// Merged QKV gemm with fused scatter + rope + q-prescale (SCALE*log2e).
// Column tile = one (tensor tt, head h). q/k/v row-major [H][4608][128].
__global__ __launch_bounds__(256, 2) void qkv_gemm(
    const void* Atxt, const void* Aimg, const void* Btxt, const void* Bimg,
    const void* rope, const void* det, int conv, uint16_t* qb, uint16_t* kb,
    uint16_t* vb) {
  __shared__ uint16_t sA[128 * 32], sB[128 * 32];
  const bool dbf = detect_bf16(det);      // original input dtype (rope)
  const bool bf = conv ? true : dbf;      // A/B operand dtype
  const int bmb = blockIdx.y;
  const long g0 = (long)bmb * 128;        // global seq row of this block
  const bool is_img = bmb >= 4;           // 4*128 == 512 txt rows
  const void* A = is_img ? Aimg : Atxt;
  const void* B = is_img ? Bimg : Btxt;
  const long bmA = is_img ? g0 - 512 : g0;
  const long bn = (long)blockIdx.x * 128;
  floatx4 acc[4][4] = {};
  gemm_core(A, B, bf, bf, bmA, bn, 1536, sA, sB, acc);

  const int t = threadIdx.x, lane = t & 63, wave = t >> 6;
  const int l16 = lane & 15, quad = lane >> 4;
  const int wm = (wave >> 1) * 64, wn = (wave & 1) * 64;
  const int th = blockIdx.x;
  const int tt = th / 12, h = th - tt * 12;
  uint16_t* dst = tt == 0 ? qb : (tt == 1 ? kb : vb);
  const bool do_rope = is_img && (tt < 2);
#pragma unroll
  for (int i = 0; i < 4; ++i)
#pragma unroll
    for (int j = 0; j < 4; ++j)
#pragma unroll
      for (int r = 0; r < 4; ++r) {
        long g = g0 + wm + i * 16 + quad * 4 + r;  // global seq row
        int d = wn + j * 16 + l16;
        float v = acc[i][j][r];
        float p = __shfl_xor(v, 1);  // partner element of the rope pair
        if (do_rope) {
          int dp = d & ~1;
          long ri = (g - 512) * 128 + dp;
          float cc = loadElem(rope, ri, dbf);
          float ss = loadElem(rope, ri + 1, dbf);
          v = (d & 1) ? (v * cc + p * ss) : (v * cc - p * ss);
        }
        if (tt == 0) v *= 0.12751745f;  // D^-0.5 * log2(e)
        dst[((long)h * 4608 + g) * 128 + d] = f2bf(v);
      }
}

// ---------------------------------------------------------------------------
// Merged out-projection gemm.
__global__ __launch_bounds__(256, 2) void out_gemm(
    const uint16_t* Abf, const void* Btxt, const void* Bimg, const void* det,
    int conv, void* out) {
  __shared__ uint16_t sA[128 * 32], sB[128 * 32];
  const bool dbf = detect_bf16(det);
  const bool bbf = conv ? true : dbf;
  const int bmb = blockIdx.y;
  const long bm = (long)bmb * 128;
  const void* B = bmb >= 4 ? Bimg : Btxt;
  const long bn = (long)blockIdx.x * 128;
  floatx4 acc[4][4] = {};
  gemm_core(Abf, B, true, bbf, bm, bn, 1536, sA, sB, acc);

  const int t = threadIdx.x, lane = t & 63, wave = t >> 6;
  const int l16 = lane & 15, quad = lane >> 4;
  const int wm = (wave >> 1) * 64, wn = (wave & 1) * 64;
#pragma unroll
  for (int i = 0; i < 4; ++i)
#pragma unroll
    for (int j = 0; j < 4; ++j)
#pragma unroll
      for (int r = 0; r < 4; ++r) {
        long row = bm + wm + i * 16 + quad * 4 + r;
        long col = bn + wn + j * 16 + l16;
        long idx = row * 1536 + col;
        if (dbf) ((uint16_t*)out)[idx] = f2bf(acc[i][j][r]);
        else ((float*)out)[idx] = acc[i][j][r];
      }
}

// ---------------------------------------------------------------------------
// Flash attention, KVBLK=64, single-buffered LDS (40KB), register prefetch.
// Block = (64 q-rows, head); 4 waves x 16 q-rows. Two barriers per 64-key
// tile; tile kt+1 global loads issued at top of tile kt. V pack VALU hoisted
// before the first barrier (overlaps PV MFMA drain; vmcnt wait lands there).
// XCD swizzle: 864 blocks = 8 XCDs x 108 contiguous (~1.5 heads/XCD).
// Q pre-scaled by SCALE*log2e -> softmax in exp2 domain. Defer-max THR=11.5.
__global__ __launch_bounds__(256, 3) void attn(
    const uint16_t* __restrict__ qb, const uint16_t* __restrict__ kb,
    const uint16_t* __restrict__ vb, uint16_t* __restrict__ ob) {
  __shared__ uint16_t sK[64 * 128];    // 16KB
  __shared__ uint16_t sVt[128 * 64];   // 16KB, [d][64 keys] chunk-swizzled
  __shared__ uint16_t sP[4][16 * 64];  // 8KB

  const int t = threadIdx.x;
  const int lane = t & 63, wave = t >> 6;
  const int l16 = lane & 15, quad = lane >> 4;
  // XCD swizzle: bijective since 864 % 8 == 0 (108 blocks per XCD chunk)
  const int bid = blockIdx.y * 72 + blockIdx.x;
  const int sw = (bid & 7) * 108 + (bid >> 3);
  const int h = sw / 72;
  const int q0 = (sw - h * 72) * 64 + wave * 16;

  const uint16_t* Qh = qb + (long)h * 4608 * 128;
  const uint16_t* Kh = kb + (long)h * 4608 * 128;
  const uint16_t* Vh = vb + (long)h * 4608 * 128;

  short8 aq[4];
#pragma unroll
  for (int dk = 0; dk < 4; ++dk)
    aq[dk] = *(const short8*)(Qh + (long)(q0 + l16) * 128 + dk * 32 + quad * 8);

  short8 ones;
#pragma unroll
  for (int j = 0; j < 8; ++j) ones[j] = (short)0x3F80;  // bf16 1.0

  float m_i[4] = {-1e30f, -1e30f, -1e30f, -1e30f};
  floatx4 accL = {};
  floatx4 accO[8] = {};

  const int krow = t >> 2;        // 0..63
  const int kcb = (t & 3) * 4;    // K chunk base (4 chunks of 8 elems)
  const int vk = (t & 31) * 2;    // V key pair
  const int vdb = (t >> 5) * 16;  // V d base (16 d's per thread)

  uint16_t* pw = &sP[wave][0];

  short8 kreg[4], vreg[4];
  uint32_t vpk[16];

  auto loadKV = [&](int key0) {
    const uint16_t* kp = Kh + (long)(key0 + krow) * 128 + kcb * 8;
    kreg[0] = *(const short8*)(kp);
    kreg[1] = *(const short8*)(kp + 8);
    kreg[2] = *(const short8*)(kp + 16);
    kreg[3] = *(const short8*)(kp + 24);
    const uint16_t* vp = Vh + (long)(key0 + vk) * 128 + vdb;
    vreg[0] = *(const short8*)(vp);
    vreg[1] = *(const short8*)(vp + 8);
    vreg[2] = *(const short8*)(vp + 128);
    vreg[3] = *(const short8*)(vp + 136);
  };
  // pack V key-pairs into u32 (VALU; overlaps PV MFMA drain; vreg dies here)
  auto packV = [&]() {
#pragma unroll
    for (int hf = 0; hf < 2; ++hf)
#pragma unroll
      for (int j = 0; j < 8; ++j)
        vpk[hf * 8 + j] = (uint16_t)vreg[hf][j] |
                          ((uint32_t)(uint16_t)vreg[2 + hf][j] << 16);
  };
  // serial window: pure LDS stores
  auto writeKV = [&]() {
#pragma unroll
    for (int j = 0; j < 4; ++j)
      *(short8*)(sK + krow * 128 + (((kcb + j) ^ (krow & 15)) * 8)) = kreg[j];
    char* vd = (char*)&sVt[0];
#pragma unroll
    for (int hf = 0; hf < 2; ++hf)
#pragma unroll
      for (int j = 0; j < 8; ++j) {
        const int d = vdb + hf * 8 + j;
        *(uint32_t*)(vd + d * 128 + (((vk >> 3) ^ (d & 7)) * 16) +
                     (vk & 7) * 2) = vpk[hf * 8 + j];
      }
  };

  loadKV(0);
  packV();
  writeKV();
  __syncthreads();

  for (int kt = 0; kt < 72; ++kt) {
    // issue next tile's global loads; they land during this tile's compute
    if (kt < 71) loadKV((kt + 1) * 64);

    // S = Q K^T (already in log2 domain)
    floatx4 sc4[4] = {};
    __builtin_amdgcn_s_setprio(1);
#pragma unroll
    for (int ns = 0; ns < 4; ++ns) {
      const int row = ns * 16 + l16;
#pragma unroll
      for (int dk = 0; dk < 4; ++dk) {
        short8 bk = *(const short8*)(sK + row * 128 +
                                     (((dk * 4 + quad) ^ l16) * 8));
        sc4[ns] = __builtin_amdgcn_mfma_f32_16x16x32_bf16(aq[dk], bk, sc4[ns],
                                                          0, 0, 0);
      }
    }
    __builtin_amdgcn_s_setprio(0);

    // online softmax (log2 domain), defer-max
    float mx[4];
#pragma unroll
    for (int r = 0; r < 4; ++r) {
      float a = fmaxf(fmaxf(sc4[0][r], sc4[1][r]),
                      fmaxf(sc4[2][r], sc4[3][r]));
      a = fmaxf(a, __shfl_xor(a, 1));
      a = fmaxf(a, __shfl_xor(a, 2));
      a = fmaxf(a, __shfl_xor(a, 4));
      a = fmaxf(a, __shfl_xor(a, 8));
      mx[r] = a;
    }
    float ex = fmaxf(fmaxf(mx[0] - m_i[0], mx[1] - m_i[1]),
                     fmaxf(mx[2] - m_i[2], mx[3] - m_i[3]));
    if (!__all(ex <= 11.5f)) {
#pragma unroll
      for (int r = 0; r < 4; ++r) {
        float mn = fmaxf(m_i[r], mx[r]);
        float al = exp2f(m_i[r] - mn);
        m_i[r] = mn;
        accL[r] *= al;
#pragma unroll
        for (int vt = 0; vt < 8; ++vt) accO[vt][r] *= al;
      }
    }
#pragma unroll
    for (int ns = 0; ns < 4; ++ns)
#pragma unroll
      for (int r = 0; r < 4; ++r) sc4[ns][r] = exp2f(sc4[ns][r] - m_i[r]);

    // P -> per-wave stash (C->A transpose), chunk-swizzled (8 chunks/row)
#pragma unroll
    for (int ns = 0; ns < 4; ++ns)
#pragma unroll
      for (int r = 0; r < 4; ++r) {
        const int row = quad * 4 + r;
        const int col = ns * 16 + l16;
        *(uint16_t*)((char*)pw + row * 128 +
                     (((col >> 3) ^ (row & 7)) * 16) + (col & 7) * 2) =
            f2bf(sc4[ns][r]);
      }
    asm volatile("s_waitcnt lgkmcnt(0)" ::: "memory");  // stash drain

    short8 pa[2];
#pragma unroll
    for (int ks = 0; ks < 2; ++ks)
      pa[ks] = *(const short8*)((char*)pw + l16 * 128 +
                                (((ks * 4 + quad) ^ (l16 & 7)) * 16));
    __builtin_amdgcn_s_setprio(1);
    accL = __builtin_amdgcn_mfma_f32_16x16x32_bf16(pa[0], ones, accL, 0, 0, 0);
    accL = __builtin_amdgcn_mfma_f32_16x16x32_bf16(pa[1], ones, accL, 0, 0, 0);
#pragma unroll
    for (int vt = 0; vt < 8; ++vt) {
      const int d = vt * 16 + l16;
#pragma unroll
      for (int ks = 0; ks < 2; ++ks) {
        short8 bv = *(const short8*)((const char*)&sVt[0] + d * 128 +
                                     (((ks * 4 + quad) ^ (d & 7)) * 16));
        accO[vt] = __builtin_amdgcn_mfma_f32_16x16x32_bf16(pa[ks], bv,
                                                           accO[vt], 0, 0, 0);
      }
    }
    __builtin_amdgcn_s_setprio(0);

    // pack next tile's V while PV MFMAs drain (vmcnt wait overlaps MFMA)
    if (kt < 71) packV();

    __syncthreads();  // all waves done reading sK/sVt
    if (kt < 71) {
      writeKV();      // pure LDS stores
      __syncthreads();
    }
  }

#pragma unroll
  for (int r = 0; r < 4; ++r) {
    const long row = q0 + quad * 4 + r;
    const float inv = 1.f / accL[r];
#pragma unroll
    for (int vt = 0; vt < 8; ++vt)
      ob[row * 1536 + h * 128 + vt * 16 + l16] = f2bf(accO[vt][r] * inv);
  }
}

// ---------------------------------------------------------------------------
extern "C" void kernel_launch(void* const* d_in, const int* in_sizes, int n_in,
                              void* d_out, int out_size, void* d_ws,
                              size_t ws_size, hipStream_t stream) {
  const void* txt = d_in[0];
  const void* img = d_in[1];
  const void* rope = d_in[2];
  const void* Wtq = d_in[3];
  const void* Wiq = d_in[4];
  const void* Wto = d_in[5];
  const void* Wio = d_in[6];

  uint16_t* ws = (uint16_t*)d_ws;
  uint16_t* qb = ws;                  // [12][4608][128]
  uint16_t* kb = ws + 7077888L;
  uint16_t* vb = ws + 14155776L;      // [12][4608][128] row-major
  uint16_t* ob = ws + 21233664L;      // [4608][1536]

  const size_t NEED = 108527616ULL;   // 54,263,808 u16 elems
  const int conv = (ws_size >= NEED) ? 1 : 0;

  const void *Atxt = txt, *Aimg = img;
  const void *Bqt = Wtq, *Bqi = Wiq, *Bot = Wto, *Boi = Wio;
  if (conv) {
    convert6<<<dim3(864, 6), 256, 0, stream>>>(txt, img, Wtq, Wiq, Wto, Wio,
                                               ws);
    Atxt = ws + 28311552L;
    Aimg = ws + 29097984L;
    Bqt = ws + 35389440L;
    Bqi = ws + 42467328L;
    Bot = ws + 49545216L;
    Boi = ws + 51904512L;
  }

  qkv_gemm<<<dim3(36, 36), 256, 0, stream>>>(Atxt, Aimg, Bqt, Bqi, rope, txt,
                                             conv, qb, kb, vb);
  attn<<<dim3(72, 12), 256, 0, stream>>>(qb, kb, vb, ob);
  out_gemm<<<dim3(12, 36), 256, 0, stream>>>(ob, Bot, Boi, txt, conv, d_out);
}

// Round 10
// 570.321 us; speedup vs baseline: 1.6105x; 1.1043x over previous
//
#include <hip/hip_runtime.h>
#include <hip/hip_bf16.h>
#include <stdint.h>

// JointAttention: B=1, L=512(txt), N=4096(img), HID=1536, H=12, D=128
// Round 12 = Round 11 resubmission (R11 bench died on GPUAcquisitionTimeout,
// broker at capacity — kernel never ran; fragment algebra re-audited OK).
//  - attn on 32x32x16 MFMA with SWAPPED operands: QK^T = mfma(K,Q) -> q
//    lane-local -> in-register softmax; P^T via 8 pack + 8 shfl_xor; PV =
//    mfma(V^T,P^T). sP stash + lgkmcnt(0) drain deleted. 2x FLOP/LDS-byte
//    (R8: LDS pipe ~41% busy was top resource; MFMA 5%, VALU 11%).
//  - 4 waves = (2 q-halves x 2 key-halves), independent online softmax per
//    key-half, exact epilogue merge.
//  - Staging, KVBLK=64, defer-max, exp2 domain, XCD swizzle identical to
//    measured R4/R8. launch_bounds(256,2). GEMMs unchanged.
// ws (u16 elems): qb[0) kb[7077888) vb[14155776) ob[21233664)
//   txtb[28311552) imgb[29097984) Wqtb[35389440) Wqib[42467328)
//   Wotb[49545216) Woib[51904512) end 54263808 -> 108.5 MB.

typedef __attribute__((ext_vector_type(8))) short short8;
typedef __attribute__((ext_vector_type(4))) float floatx4;
typedef __attribute__((ext_vector_type(16))) float floatx16;

#define DEV __device__ __forceinline__

DEV float bf2f(uint16_t s) {
  union { uint32_t u; float f; } v;
  v.u = (uint32_t)s << 16;
  return v.f;
}
DEV uint16_t f2bf(float f) {
  __hip_bfloat16 h = __float2bfloat16(f);
  return __builtin_bit_cast(uint16_t, h);
}
DEV uint32_t pk2(float a, float b) {
  return (uint32_t)f2bf(a) | ((uint32_t)f2bf(b) << 16);
}

// Distinguish bf16 vs fp32 buffers (majority vote on exponent sanity).
DEV bool detect_bf16(const void* p) {
  const uint16_t* u = (const uint16_t*)p;
  int sane = 0;
  for (int i = 0; i < 64; ++i) {
    int e = (u[2 * i] >> 7) & 0xFF;
    sane += (e > 90 && e < 145) ? 1 : 0;
  }
  return sane >= 40;
}

DEV short8 load8(const void* base, long idx, bool bf) {
  if (bf) return *(const short8*)((const uint16_t*)base + idx);
  const floatx4* f = (const floatx4*)((const float*)base + idx);
  floatx4 a = f[0], b = f[1];
  short8 r;
  r[0] = (short)f2bf(a[0]); r[1] = (short)f2bf(a[1]);
  r[2] = (short)f2bf(a[2]); r[3] = (short)f2bf(a[3]);
  r[4] = (short)f2bf(b[0]); r[5] = (short)f2bf(b[1]);
  r[6] = (short)f2bf(b[2]); r[7] = (short)f2bf(b[3]);
  return r;
}

DEV float loadElem(const void* base, long idx, bool bf) {
  return bf ? bf2f(((const uint16_t*)base)[idx]) : ((const float*)base)[idx];
}

// ---------------------------------------------------------------------------
// One-time fp32->bf16 (or bf16 copy) of the 6 GEMM operand tensors into ws.
__global__ void convert6(const void* s0, const void* s1, const void* s2,
                         const void* s3, const void* s4, const void* s5,
                         uint16_t* ws) {
  const void* s;
  uint16_t* d;
  long n;
  switch (blockIdx.y) {
    case 0: s = s0; d = ws + 28311552L; n = 786432L; break;   // txt
    case 1: s = s1; d = ws + 29097984L; n = 6291456L; break;  // img
    case 2: s = s2; d = ws + 35389440L; n = 7077888L; break;  // W_txt_qkv
    case 3: s = s3; d = ws + 42467328L; n = 7077888L; break;  // W_img_qkv
    case 4: s = s4; d = ws + 49545216L; n = 2359296L; break;  // W_txt_out
    default: s = s5; d = ws + 51904512L; n = 2359296L; break; // W_img_out
  }
  const bool bf = detect_bf16(s);
  const long stride = (long)gridDim.x * blockDim.x * 8;
  for (long i = ((long)blockIdx.x * blockDim.x + threadIdx.x) * 8; i < n;
       i += stride) {
    if (bf) {
      *(short8*)(d + i) = *(const short8*)((const uint16_t*)s + i);
    } else {
      const floatx4* f = (const floatx4*)((const float*)s + i);
      floatx4 a = f[0], b = f[1];
      short8 r;
      r[0] = (short)f2bf(a[0]); r[1] = (short)f2bf(a[1]);
      r[2] = (short)f2bf(a[2]); r[3] = (short)f2bf(a[3]);
      r[4] = (short)f2bf(b[0]); r[5] = (short)f2bf(b[1]);
      r[6] = (short)f2bf(b[2]); r[7] = (short)f2bf(b[3]);
      *(short8*)(d + i) = r;
    }
  }
}

// ---------------------------------------------------------------------------
// acc[4][4] for C tile (bm,bn) of A[M,K] * B[N,K]^T via bf16 MFMA.
// 128x128 tile, BK=32, register staging + ds_write_b128, XOR chunk swizzle.
DEV void gemm_core(const void* A, const void* B, bool abf, bool bbf, long bm,
                   long bn, int K, uint16_t* sA, uint16_t* sB,
                   floatx4 (&acc)[4][4]) {
  const int t = threadIdx.x;
  const int lane = t & 63, wave = t >> 6, l16 = lane & 15, quad = lane >> 4;
  const int srow = t >> 2, c = t & 3, g = c ^ (srow & 3);
  const int wm = (wave >> 1) * 64, wn = (wave & 1) * 64;
  const int fsl = (quad ^ (l16 & 3)) * 8;
  for (int k0 = 0; k0 < K; k0 += 32) {
    short8 a0 = load8(A, (bm + srow) * (long)K + k0 + g * 8, abf);
    short8 a1 = load8(A, (bm + 64 + srow) * (long)K + k0 + g * 8, abf);
    short8 b0 = load8(B, (bn + srow) * (long)K + k0 + g * 8, bbf);
    short8 b1 = load8(B, (bn + 64 + srow) * (long)K + k0 + g * 8, bbf);
    __syncthreads();  // prev-iter frag reads done before overwrite
    *(short8*)(sA + srow * 32 + c * 8) = a0;
    *(short8*)(sA + (64 + srow) * 32 + c * 8) = a1;
    *(short8*)(sB + srow * 32 + c * 8) = b0;
    *(short8*)(sB + (64 + srow) * 32 + c * 8) = b1;
    __syncthreads();
    short8 af[4], bfr[4];
#pragma unroll
    for (int i = 0; i < 4; ++i) {
      af[i] = *(const short8*)(sA + (wm + i * 16 + l16) * 32 + fsl);
      bfr[i] = *(const short8*)(sB + (wn + i * 16 + l16) * 32 + fsl);
    }
#pragma unroll
    for (int i = 0; i < 4; ++i)
#pragma unroll
      for (int j = 0; j < 4; ++j)
        acc[i][j] = __builtin_amdgcn_mfma_f32_16x16x32_bf16(af[i], bfr[j],
                                                            acc[i][j], 0, 0, 0);
  }
}

// ---------------------------------------------------------------------------
// Merged QKV gemm with fused scatter + rope + q-prescale (SCALE*log2e).
// Column tile = one (tensor tt, head h). q/k/v row-major [H][4608][128].
__global__ __launch_bounds__(256, 2) void qkv_gemm(
    const void* Atxt, const void* Aimg, const void* Btxt, const void* Bimg,
    const void* rope, const void* det, int conv, uint16_t* qb, uint16_t* kb,
    uint16_t* vb) {
  __shared__ uint16_t sA[128 * 32], sB[128 * 32];
  const bool dbf = detect_bf16(det);      // original input dtype (rope)
  const bool bf = conv ? true : dbf;      // A/B operand dtype
  const int bmb = blockIdx.y;
  const long g0 = (long)bmb * 128;        // global seq row of this block
  const bool is_img = bmb >= 4;           // 4*128 == 512 txt rows
  const void* A = is_img ? Aimg : Atxt;
  const void* B = is_img ? Bimg : Btxt;
  const long bmA = is_img ? g0 - 512 : g0;
  const long bn = (long)blockIdx.x * 128;
  floatx4 acc[4][4] = {};
  gemm_core(A, B, bf, bf, bmA, bn, 1536, sA, sB, acc);

  const int t = threadIdx.x, lane = t & 63, wave = t >> 6;
  const int l16 = lane & 15, quad = lane >> 4;
  const int wm = (wave >> 1) * 64, wn = (wave & 1) * 64;
  const int th = blockIdx.x;
  const int tt = th / 12, h = th - tt * 12;
  uint16_t* dst = tt == 0 ? qb : (tt == 1 ? kb : vb);
  const bool do_rope = is_img && (tt < 2);
#pragma unroll
  for (int i = 0; i < 4; ++i)
#pragma unroll
    for (int j = 0; j < 4; ++j)
#pragma unroll
      for (int r = 0; r < 4; ++r) {
        long g = g0 + wm + i * 16 + quad * 4 + r;  // global seq row
        int d = wn + j * 16 + l16;
        float v = acc[i][j][r];
        float p = __shfl_xor(v, 1);  // partner element of the rope pair
        if (do_rope) {
          int dp = d & ~1;
          long ri = (g - 512) * 128 + dp;
          float cc = loadElem(rope, ri, dbf);
          float ss = loadElem(rope, ri + 1, dbf);
          v = (d & 1) ? (v * cc + p * ss) : (v * cc - p * ss);
        }
        if (tt == 0) v *= 0.12751745f;  // D^-0.5 * log2(e)
        dst[((long)h * 4608 + g) * 128 + d] = f2bf(v);
      }
}

// ---------------------------------------------------------------------------
// Merged out-projection gemm.
__global__ __launch_bounds__(256, 2) void out_gemm(
    const uint16_t* Abf, const void* Btxt, const void* Bimg, const void* det,
    int conv, void* out) {
  __shared__ uint16_t sA[128 * 32], sB[128 * 32];
  const bool dbf = detect_bf16(det);
  const bool bbf = conv ? true : dbf;
  const int bmb = blockIdx.y;
  const long bm = (long)bmb * 128;
  const void* B = bmb >= 4 ? Bimg : Btxt;
  const long bn = (long)blockIdx.x * 128;
  floatx4 acc[4][4] = {};
  gemm_core(Abf, B, true, bbf, bm, bn, 1536, sA, sB, acc);

  const int t = threadIdx.x, lane = t & 63, wave = t >> 6;
  const int l16 = lane & 15, quad = lane >> 4;
  const int wm = (wave >> 1) * 64, wn = (wave & 1) * 64;
#pragma unroll
  for (int i = 0; i < 4; ++i)
#pragma unroll
    for (int j = 0; j < 4; ++j)
#pragma unroll
      for (int r = 0; r < 4; ++r) {
        long row = bm + wm + i * 16 + quad * 4 + r;
        long col = bn + wn + j * 16 + l16;
        long idx = row * 1536 + col;
        if (dbf) ((uint16_t*)out)[idx] = f2bf(acc[i][j][r]);
        else ((float*)out)[idx] = acc[i][j][r];
      }
}

// ---------------------------------------------------------------------------
// Flash attention, 32x32x16 MFMA, swapped operands, KVBLK=64.
// Block = 64 q-rows; 4 waves = (wq q-half) x (wk key-half): wave covers
// 32 q x 32 keys/tile with independent online softmax per key-half;
// exact merge at epilogue. Lane l: q = q0w + (l&31), hi = l>>5.
// QK: sc = mfma(K-frag, Q-frag): C[key][q], col=q lane-local.
//   P keys (per lane) = kb0 + (r&3)+8*(r>>2)+4*hi for reg r.
// PV: accO[g] = mfma(V^T-frag, P^T-frag): C[d][q], col=q lane-local.
// Staging/swizzles identical to R4/R8 measured kernel. XCD swizzle kept.
__global__ __launch_bounds__(256, 2) void attn(
    const uint16_t* __restrict__ qb, const uint16_t* __restrict__ kb,
    const uint16_t* __restrict__ vb, uint16_t* __restrict__ ob) {
  __shared__ __align__(16) char smem[34304];
  uint16_t* sK = (uint16_t*)smem;              // [64][128] chunk-swizzled
  uint16_t* sVt = (uint16_t*)(smem + 16384);   // [128 d][64 keys] packed
  float* sO = (float*)smem;                    // epilogue reuse (2x32x130)
  float* sML = (float*)(smem + 33280);         // [4 waves][32 q][2]

  const int t = threadIdx.x;
  const int lane = t & 63, wave = t >> 6;
  const int l31 = lane & 31, hi = lane >> 5;
  const int wq = wave >> 1, wk = wave & 1;
  const int kb0 = wk * 32;
  // XCD swizzle: bijective since 864 % 8 == 0
  const int bid = blockIdx.y * 72 + blockIdx.x;
  const int sw = (bid & 7) * 108 + (bid >> 3);
  const int h = sw / 72;
  const int q0 = (sw - h * 72) * 64 + wq * 32;

  const uint16_t* Qh = qb + (long)h * 4608 * 128;
  const uint16_t* Kh = kb + (long)h * 4608 * 128;
  const uint16_t* Vh = vb + (long)h * 4608 * 128;

  // Q as B-fragments: aq[dk] = Q[q0+l31][dk*16 + hi*8 .. +8]
  short8 aq[8];
#pragma unroll
  for (int dk = 0; dk < 8; ++dk)
    aq[dk] = *(const short8*)(Qh + (long)(q0 + l31) * 128 + dk * 16 + hi * 8);

  float m_i = -1e30f;
  float accL = 0.f;
  floatx16 accO[4] = {};  // accO[g][r]: d = g*32 + (r&3)+8*(r>>2)+4*hi

  // staging (identical to R4/R8)
  const int krow = t >> 2;        // 0..63
  const int kcb = (t & 3) * 4;    // K chunk base (4 chunks of 8 elems)
  const int vk = (t & 31) * 2;    // V key pair
  const int vdb = (t >> 5) * 16;  // V d base (16 d's per thread)

  short8 kreg[4], vreg[4];

  auto loadKV = [&](int key0) {
    const uint16_t* kp = Kh + (long)(key0 + krow) * 128 + kcb * 8;
    kreg[0] = *(const short8*)(kp);
    kreg[1] = *(const short8*)(kp + 8);
    kreg[2] = *(const short8*)(kp + 16);
    kreg[3] = *(const short8*)(kp + 24);
    const uint16_t* vp = Vh + (long)(key0 + vk) * 128 + vdb;
    vreg[0] = *(const short8*)(vp);
    vreg[1] = *(const short8*)(vp + 8);
    vreg[2] = *(const short8*)(vp + 128);
    vreg[3] = *(const short8*)(vp + 136);
  };
  auto writeKV = [&]() {
#pragma unroll
    for (int j = 0; j < 4; ++j)
      *(short8*)(sK + krow * 128 + (((kcb + j) ^ (krow & 15)) * 8)) = kreg[j];
    char* vd = (char*)sVt;
#pragma unroll
    for (int hf = 0; hf < 2; ++hf)
#pragma unroll
      for (int j = 0; j < 8; ++j) {
        const int d = vdb + hf * 8 + j;
        uint32_t pk = (uint16_t)vreg[hf][j] |
                      ((uint32_t)(uint16_t)vreg[2 + hf][j] << 16);
        *(uint32_t*)(vd + d * 128 + (((vk >> 3) ^ (d & 7)) * 16) +
                     (vk & 7) * 2) = pk;
      }
  };

  loadKV(0);
  writeKV();
  __syncthreads();

  for (int kt = 0; kt < 72; ++kt) {
    if (kt < 71) loadKV((kt + 1) * 64);

    // S^T = K Q^T (exp2 domain; Q pre-scaled). sc[r]: key kb0+crow(r,hi), q=l31
    floatx16 sc = {};
    __builtin_amdgcn_s_setprio(1);
#pragma unroll
    for (int dk = 0; dk < 8; ++dk) {
      short8 ak = *(const short8*)(
          sK + (kb0 + l31) * 128 + (((dk * 2 + hi) ^ (l31 & 15)) * 8));
      sc = __builtin_amdgcn_mfma_f32_32x32x16_bf16(ak, aq[dk], sc, 0, 0, 0);
    }
    __builtin_amdgcn_s_setprio(0);

    // in-register online softmax (this wave's 32 keys of lane's q-row)
    float mx = sc[0];
#pragma unroll
    for (int r = 1; r < 16; ++r) mx = fmaxf(mx, sc[r]);
    mx = fmaxf(mx, __shfl_xor(mx, 32));
    if (!__all(mx - m_i <= 11.5f)) {
      float mn = fmaxf(m_i, mx);
      float al = exp2f(m_i - mn);
      m_i = mn;
      accL *= al;
#pragma unroll
      for (int g = 0; g < 4; ++g)
#pragma unroll
        for (int r = 0; r < 16; ++r) accO[g][r] *= al;
    }
#pragma unroll
    for (int r = 0; r < 16; ++r) sc[r] = exp2f(sc[r] - m_i);
    float s = 0.f;
#pragma unroll
    for (int r = 0; r < 16; ++r) s += sc[r];
    accL += s + __shfl_xor(s, 32);

    // build P^T B-fragments pb[s'] (keys kb0 + s'*16 + hi*8 + 0..7)
    short8 pb[2];
#pragma unroll
    for (int sp = 0; sp < 2; ++sp) {
      uint32_t cA = pk2(sc[sp * 8 + 0], sc[sp * 8 + 1]);
      uint32_t cB = pk2(sc[sp * 8 + 2], sc[sp * 8 + 3]);
      uint32_t cC = pk2(sc[sp * 8 + 4], sc[sp * 8 + 5]);
      uint32_t cD = pk2(sc[sp * 8 + 6], sc[sp * 8 + 7]);
      uint32_t xA = (uint32_t)__shfl_xor((int)cA, 32);
      uint32_t xB = (uint32_t)__shfl_xor((int)cB, 32);
      uint32_t xC = (uint32_t)__shfl_xor((int)cC, 32);
      uint32_t xD = (uint32_t)__shfl_xor((int)cD, 32);
      union { short8 v; uint32_t u[4]; } w;
      w.u[0] = hi ? xC : cA;
      w.u[1] = hi ? xD : cB;
      w.u[2] = hi ? cC : xA;
      w.u[3] = hi ? cD : xB;
      pb[sp] = w.v;
    }

    // O^T += V^T P^T : accO[g] over d-group g
    __builtin_amdgcn_s_setprio(1);
#pragma unroll
    for (int g = 0; g < 4; ++g) {
      const int d = g * 32 + l31;
#pragma unroll
      for (int sp = 0; sp < 2; ++sp) {
        short8 av = *(const short8*)(
            (const char*)sVt + d * 128 +
            (((wk * 4 + sp * 2 + hi) ^ (d & 7)) * 16));
        accO[g] =
            __builtin_amdgcn_mfma_f32_32x32x16_bf16(av, pb[sp], accO[g], 0, 0, 0);
      }
    }
    __builtin_amdgcn_s_setprio(0);

    __syncthreads();  // all waves done reading sK/sVt
    if (kt < 71) {
      writeKV();
      __syncthreads();
    }
  }

  // ---- epilogue: merge the two key-half partials (exact) ----
  __syncthreads();
  sML[(wave * 32 + l31) * 2 + 0] = m_i;
  sML[(wave * 32 + l31) * 2 + 1] = accL;
  __syncthreads();
  const float m0 = sML[((wq * 2 + 0) * 32 + l31) * 2 + 0];
  const float l0 = sML[((wq * 2 + 0) * 32 + l31) * 2 + 1];
  const float m1 = sML[((wq * 2 + 1) * 32 + l31) * 2 + 0];
  const float l1 = sML[((wq * 2 + 1) * 32 + l31) * 2 + 1];
  const float M = fmaxf(m0, m1);
  const float L = l0 * exp2f(m0 - M) + l1 * exp2f(m1 - M);
  const float fac = exp2f(m_i - M);
  float* myO = sO + wq * 4160 + l31 * 130;  // stride 130 (bank-friendly)
  if (wk == 1) {
#pragma unroll
    for (int g = 0; g < 4; ++g)
#pragma unroll
      for (int r = 0; r < 16; ++r) {
        const int d = g * 32 + (r & 3) + 8 * (r >> 2) + 4 * hi;
        myO[d] = accO[g][r] * fac;
      }
  }
  __syncthreads();
  if (wk == 0) {
    const float inv = 1.f / L;
    const long q = q0 + l31;
#pragma unroll
    for (int g = 0; g < 4; ++g)
#pragma unroll
      for (int rb = 0; rb < 4; ++rb) {
        const int d0 = g * 32 + 8 * rb + 4 * hi;
        uint64_t pk = 0;
#pragma unroll
        for (int i = 0; i < 4; ++i) {
          float v = (accO[g][rb * 4 + i] * fac + myO[d0 + i]) * inv;
          pk |= (uint64_t)f2bf(v) << (16 * i);
        }
        *(uint64_t*)(ob + q * 1536 + h * 128 + d0) = pk;
      }
  }
}

// ---------------------------------------------------------------------------
extern "C" void kernel_launch(void* const* d_in, const int* in_sizes, int n_in,
                              void* d_out, int out_size, void* d_ws,
                              size_t ws_size, hipStream_t stream) {
  const void* txt = d_in[0];
  const void* img = d_in[1];
  const void* rope = d_in[2];
  const void* Wtq = d_in[3];
  const void* Wiq = d_in[4];
  const void* Wto = d_in[5];
  const void* Wio = d_in[6];

  uint16_t* ws = (uint16_t*)d_ws;
  uint16_t* qb = ws;                  // [12][4608][128]
  uint16_t* kb = ws + 7077888L;
  uint16_t* vb = ws + 14155776L;      // [12][4608][128] row-major
  uint16_t* ob = ws + 21233664L;      // [4608][1536]

  const size_t NEED = 108527616ULL;   // 54,263,808 u16 elems
  const int conv = (ws_size >= NEED) ? 1 : 0;

  const void *Atxt = txt, *Aimg = img;
  const void *Bqt = Wtq, *Bqi = Wiq, *Bot = Wto, *Boi = Wio;
  if (conv) {
    convert6<<<dim3(864, 6), 256, 0, stream>>>(txt, img, Wtq, Wiq, Wto, Wio,
                                               ws);
    Atxt = ws + 28311552L;
    Aimg = ws + 29097984L;
    Bqt = ws + 35389440L;
    Bqi = ws + 42467328L;
    Bot = ws + 49545216L;
    Boi = ws + 51904512L;
  }

  qkv_gemm<<<dim3(36, 36), 256, 0, stream>>>(Atxt, Aimg, Bqt, Bqi, rope, txt,
                                             conv, qb, kb, vb);
  attn<<<dim3(72, 12), 256, 0, stream>>>(qb, kb, vb, ob);
  out_gemm<<<dim3(12, 36), 256, 0, stream>>>(ob, Bot, Boi, txt, conv, d_out);
}